// Round 3
// baseline (11559.709 us; speedup 1.0000x reference)
//
#include <hip/hip_runtime.h>
#include <math.h>

// Problem constants: B=1, T=2048, D=1024, H=16, HD=64, STRIDE=8, Tg=256.
// Output 0: weighted [2048][1024]
// Output 1: combined [3][2048][2048] = (s0+s1+s3) * {linear_w, sparse_w, quantum_w}
#define D_MODEL 1024

// ---------------------------------------------------------------------------
// GEMM: C[M,N] (+)= scale * (X[M,K] @ W[N,K]^T + bias)
// ---------------------------------------------------------------------------
__global__ __launch_bounds__(256) void gemm_xwt(
    const float* __restrict__ X, int xrstride,
    const float* __restrict__ W, int wrstride,
    const float* __restrict__ bias,
    float* __restrict__ C, int M, int N, int K,
    const float* __restrict__ sptr, int sidx, int accum)
{
    __shared__ float Xs[16][68];
    __shared__ float Ws[16][68];
    const int tid = threadIdx.x;
    const int m0 = blockIdx.x * 64, n0 = blockIdx.y * 64;
    const int ty = tid >> 4, tx = tid & 15;
    float acc[4][4] = {};
    for (int k0 = 0; k0 < K; k0 += 16) {
        __syncthreads();
#pragma unroll
        for (int i = 0; i < 4; ++i) {
            int li = tid + i * 256;
            int r = li >> 4, kk = li & 15;
            Xs[kk][r] = X[(size_t)(m0 + r) * xrstride + k0 + kk];
            Ws[kk][r] = W[(size_t)(n0 + r) * wrstride + k0 + kk];
        }
        __syncthreads();
#pragma unroll
        for (int kk = 0; kk < 16; ++kk) {
            float4 a4 = *(const float4*)&Xs[kk][ty * 4];
            float4 b4 = *(const float4*)&Ws[kk][tx * 4];
            float av[4] = {a4.x, a4.y, a4.z, a4.w};
            float bv[4] = {b4.x, b4.y, b4.z, b4.w};
#pragma unroll
            for (int i = 0; i < 4; ++i)
#pragma unroll
                for (int j = 0; j < 4; ++j)
                    acc[i][j] += av[i] * bv[j];
        }
    }
    const float s = (sptr != nullptr) ? sptr[sidx] : 1.0f;
#pragma unroll
    for (int i = 0; i < 4; ++i) {
        const size_t row = (size_t)(m0 + ty * 4 + i) * N;
#pragma unroll
        for (int j = 0; j < 4; ++j) {
            const int col = n0 + tx * 4 + j;
            float v = acc[i][j] + (bias ? bias[col] : 0.0f);
            if (accum) C[row + col] += s * v;
            else       C[row + col]  = s * v;
        }
    }
}

// ---------------------------------------------------------------------------
// alpha: amode 0 -> 1; amode 1 -> mask (sigmoid>0.5 <=> x>0); amode 2 -> gate
// ---------------------------------------------------------------------------
__device__ __forceinline__ float head_alpha(const float* ap, int amode, int h) {
    if (amode == 1) return (ap[h] > 0.0f) ? 1.0f : 0.0f;
    if (amode == 2) return 1.0f / (1.0f + __expf(-ap[h * 4]));
    return 1.0f;
}

// ---------------------------------------------------------------------------
// Single-pass flash attention, one block = (head, 64 query rows).
//   O (+)= osc * softmax(ascale * Q K^T) V, written exactly once (no atomics)
//   m,l row stats written for later comb_plane use.
//   Masked heads (amode 1, alpha=0): p uniform -> skip QK/softmax, O=mean(V).
// ---------------------------------------------------------------------------
template <int HD>
__global__ __launch_bounds__(256) void flash_attn(
    const float* __restrict__ Q, const float* __restrict__ K,
    const float* __restrict__ V,
    const float* __restrict__ aparam, int amode,
    float* __restrict__ O,
    const float* __restrict__ strat, int o_sidx, int accum,
    float* __restrict__ mout, float* __restrict__ lout,
    int Tq, int Tk, float inv_scale)
{
    constexpr int ROWS = 64;
    constexpr int STILE = (HD == 64) ? 64 : 32;
    constexpr int CPT = STILE / 16;   // score cols per thread
    constexpr int PC = HD / 4;        // PV cols per thread
    __shared__ float qs[ROWS][HD + 4];
    __shared__ float ks[STILE][HD + 4];
    __shared__ float ptile[ROWS][STILE + 1];
    __shared__ float alpha_s[ROWS];
    __shared__ float linv_s[ROWS];

    const int tid = threadIdx.x;
    const int h = blockIdx.y;
    const int r0 = blockIdx.x * ROWS;
    const float ascale = head_alpha(aparam, amode, h) * inv_scale;
    const bool masked = (amode == 1) && (ascale == 0.0f);

    for (int idx = tid; idx < ROWS * HD; idx += 256) {
        int r = idx / HD, d = idx % HD;
        qs[r][d] = Q[(size_t)(r0 + r) * D_MODEL + h * HD + d];
    }
    const int ty = tid >> 4, tx = tid & 15;   // score mapping: rows ty*4+i, cols tx+16*j
    const int pr = tid >> 2, pc0 = (tid & 3) * PC;  // PV mapping

    float mreg[4], lreg[4];
#pragma unroll
    for (int i = 0; i < 4; ++i) { mreg[i] = -1e30f; lreg[i] = 0.0f; }
    float4 oacc[PC / 4];
#pragma unroll
    for (int j = 0; j < PC / 4; ++j) oacc[j] = make_float4(0.f, 0.f, 0.f, 0.f);

    for (int s0 = 0; s0 < Tk; s0 += STILE) {
        if (!masked) {
            for (int idx = tid; idx < STILE * HD; idx += 256) {
                int r = idx / HD, d = idx % HD;
                ks[r][d] = K[(size_t)(s0 + r) * D_MODEL + h * HD + d];
            }
        }
        __syncthreads();
        if (!masked) {
            float sc[4][CPT];
#pragma unroll
            for (int i = 0; i < 4; ++i)
#pragma unroll
                for (int j = 0; j < CPT; ++j) sc[i][j] = 0.0f;
            for (int d0 = 0; d0 < HD; d0 += 4) {
                float4 bv[CPT];
#pragma unroll
                for (int j = 0; j < CPT; ++j) bv[j] = *(const float4*)&ks[tx + 16 * j][d0];
#pragma unroll
                for (int i = 0; i < 4; ++i) {
                    float4 a = *(const float4*)&qs[ty * 4 + i][d0];
#pragma unroll
                    for (int j = 0; j < CPT; ++j)
                        sc[i][j] += a.x * bv[j].x + a.y * bv[j].y + a.z * bv[j].z + a.w * bv[j].w;
                }
            }
#pragma unroll
            for (int i = 0; i < 4; ++i) {
                float tm = -1e30f;
#pragma unroll
                for (int j = 0; j < CPT; ++j) { sc[i][j] *= ascale; tm = fmaxf(tm, sc[i][j]); }
#pragma unroll
                for (int off = 1; off < 16; off <<= 1) tm = fmaxf(tm, __shfl_xor(tm, off));
                float nm = fmaxf(mreg[i], tm);
                float pj[CPT];
                float ps = 0.0f;
#pragma unroll
                for (int j = 0; j < CPT; ++j) { pj[j] = __expf(sc[i][j] - nm); ps += pj[j]; }
#pragma unroll
                for (int off = 1; off < 16; off <<= 1) ps += __shfl_xor(ps, off);
                float al = __expf(mreg[i] - nm);
                lreg[i] = lreg[i] * al + ps;
                mreg[i] = nm;
#pragma unroll
                for (int j = 0; j < CPT; ++j) ptile[ty * 4 + i][tx + 16 * j] = pj[j];
                if (tx == 0) alpha_s[ty * 4 + i] = al;
            }
        }
        __syncthreads();
        // PV
        const float arow = masked ? 1.0f : alpha_s[pr];
#pragma unroll
        for (int jj = 0; jj < PC / 4; ++jj) {
            oacc[jj].x *= arow; oacc[jj].y *= arow;
            oacc[jj].z *= arow; oacc[jj].w *= arow;
        }
        for (int s = 0; s < STILE; ++s) {
            float p = masked ? 1.0f : ptile[pr][s];
            const float4* vr = (const float4*)(V + (size_t)(s0 + s) * D_MODEL + h * HD + pc0);
#pragma unroll
            for (int jj = 0; jj < PC / 4; ++jj) {
                float4 v4 = vr[jj];
                oacc[jj].x += p * v4.x; oacc[jj].y += p * v4.y;
                oacc[jj].z += p * v4.z; oacc[jj].w += p * v4.w;
            }
        }
    }
    // epilogue: stats out + normalized O write (once)
    if (tx == 0) {
#pragma unroll
        for (int i = 0; i < 4; ++i) {
            int r = ty * 4 + i;
            float lf = masked ? (float)Tk : lreg[i];
            mout[h * Tq + r0 + r] = masked ? 0.0f : mreg[i];
            lout[h * Tq + r0 + r] = lf;
            linv_s[r] = 1.0f / lf;
        }
    }
    __syncthreads();
    const float inv = linv_s[pr];
    const float osc = ((o_sidx >= 0) ? strat[o_sidx] : 1.0f) * inv;
    float4* orow = (float4*)(O + (size_t)(r0 + pr) * D_MODEL + h * HD + pc0);
#pragma unroll
    for (int jj = 0; jj < PC / 4; ++jj) {
        float4 v;
        v.x = osc * oacc[jj].x; v.y = osc * oacc[jj].y;
        v.z = osc * oacc[jj].z; v.w = osc * oacc[jj].w;
        if (accum) {
            float4 old = orow[jj];
            v.x += old.x; v.y += old.y; v.z += old.z; v.w += old.w;
        }
        orow[jj] = v;
    }
}

// ---------------------------------------------------------------------------
// comb plane: comb[r][c] = csc * sum_h exp(ascale*q_h.k_h - m)/l
// Block = 64 rows x 128 cols; loops all 16 heads (HD=64 only). One store per
// element, no RMW. Masked heads contribute exact uniform 1/Tk.
// ---------------------------------------------------------------------------
__global__ __launch_bounds__(256) void comb_plane(
    const float* __restrict__ Q, const float* __restrict__ K,
    const float* __restrict__ mrow, const float* __restrict__ lrow,
    const float* __restrict__ aparam, int amode,
    const float* __restrict__ strat,
    float* __restrict__ comb, int Tq, int Tk, int nh, float inv_scale)
{
    __shared__ float qs[64][68];
    __shared__ float ks[128][68];
    __shared__ float mls[64][2];
    const int tid = threadIdx.x;
    const int r0 = blockIdx.x * 64, c0 = blockIdx.y * 128;
    const int ty = tid >> 4, tx = tid & 15;   // rows ty*4+i, cols tx+16*j
    float acc[4][8] = {};
    float unif = 0.0f;
    for (int h = 0; h < nh; ++h) {
        const float ascale = head_alpha(aparam, amode, h) * inv_scale;
        if (amode == 1 && ascale == 0.0f) { unif += 1.0f; continue; }
        for (int idx = tid; idx < 64 * 64; idx += 256) {
            int r = idx >> 6, d = idx & 63;
            qs[r][d] = Q[(size_t)(r0 + r) * D_MODEL + h * 64 + d];
        }
        for (int idx = tid; idx < 128 * 64; idx += 256) {
            int r = idx >> 6, d = idx & 63;
            ks[r][d] = K[(size_t)(c0 + r) * D_MODEL + h * 64 + d];
        }
        if (tid < 64) {
            mls[tid][0] = mrow[h * Tq + r0 + tid];
            mls[tid][1] = 1.0f / lrow[h * Tq + r0 + tid];
        }
        __syncthreads();
        float sc[4][8] = {};
        for (int d0 = 0; d0 < 64; d0 += 4) {
            float4 bv[8];
#pragma unroll
            for (int j = 0; j < 8; ++j) bv[j] = *(const float4*)&ks[tx + 16 * j][d0];
#pragma unroll
            for (int i = 0; i < 4; ++i) {
                float4 a = *(const float4*)&qs[ty * 4 + i][d0];
#pragma unroll
                for (int j = 0; j < 8; ++j)
                    sc[i][j] += a.x * bv[j].x + a.y * bv[j].y + a.z * bv[j].z + a.w * bv[j].w;
            }
        }
#pragma unroll
        for (int i = 0; i < 4; ++i) {
            const float mm = mls[ty * 4 + i][0], li = mls[ty * 4 + i][1];
#pragma unroll
            for (int j = 0; j < 8; ++j)
                acc[i][j] += __expf(sc[i][j] * ascale - mm) * li;
        }
        __syncthreads();
    }
    const float csc = (strat[0] + strat[1] + strat[3]) / (float)nh;
    const float uadd = unif / (float)Tk;
#pragma unroll
    for (int i = 0; i < 4; ++i) {
        float* crow = comb + (size_t)(r0 + ty * 4 + i) * Tk + c0 + tx;
#pragma unroll
        for (int j = 0; j < 8; ++j)
            crow[16 * j] = csc * (acc[i][j] + uadd);
    }
}

// ---------------------------------------------------------------------------
// Per-head 64x64 rotation: Y[t][h*64+e] = sum_d X[t][h*64+d] * R[h][d][e]
// ---------------------------------------------------------------------------
__global__ __launch_bounds__(256) void rotate_heads(
    const float* __restrict__ X, const float* __restrict__ R,
    float* __restrict__ Y)
{
    __shared__ float Rt[64][68];
    __shared__ float xs[64][68];
    const int tid = threadIdx.x;
    const int h = blockIdx.y;
    const int t0 = blockIdx.x * 64;
    for (int idx = tid; idx < 4096; idx += 256) {
        int d = idx >> 6, e = idx & 63;
        Rt[e][d] = R[h * 4096 + idx];
        xs[d][e] = X[(size_t)(t0 + d) * D_MODEL + h * 64 + e];
    }
    __syncthreads();
    const int ty = tid >> 4, tx = tid & 15;
    float acc[4][4] = {};
    for (int d0 = 0; d0 < 64; d0 += 4) {
        float4 rv[4];
#pragma unroll
        for (int j = 0; j < 4; ++j) rv[j] = *(const float4*)&Rt[tx * 4 + j][d0];
#pragma unroll
        for (int i = 0; i < 4; ++i) {
            float4 a = *(const float4*)&xs[ty * 4 + i][d0];
#pragma unroll
            for (int j = 0; j < 4; ++j)
                acc[i][j] += a.x * rv[j].x + a.y * rv[j].y + a.z * rv[j].z + a.w * rv[j].w;
        }
    }
#pragma unroll
    for (int i = 0; i < 4; ++i)
#pragma unroll
        for (int j = 0; j < 4; ++j)
            Y[(size_t)(t0 + ty * 4 + i) * D_MODEL + h * 64 + tx * 4 + j] = acc[i][j];
}

// ---------------------------------------------------------------------------
// F.interpolate(mode='linear', align_corners=False): [256,1024] -> [2048,1024]
// ---------------------------------------------------------------------------
__global__ __launch_bounds__(256) void interp_lin(
    const float* __restrict__ G, float* __restrict__ out)
{
    const int t = blockIdx.x;
    float src = (t + 0.5f) * 0.125f - 0.5f;
    src = fminf(fmaxf(src, 0.0f), 255.0f);
    float fl = floorf(src);
    int i0 = (int)fl;
    int i1 = min(i0 + 1, 255);
    float w = src - fl;
    const float4* g0 = (const float4*)(G + (size_t)i0 * D_MODEL);
    const float4* g1 = (const float4*)(G + (size_t)i1 * D_MODEL);
    float4* o = (float4*)(out + (size_t)t * D_MODEL);
    int c = threadIdx.x;
    float4 a = g0[c], b = g1[c];
    float4 r;
    r.x = a.x * (1.0f - w) + b.x * w;
    r.y = a.y * (1.0f - w) + b.y * w;
    r.z = a.z * (1.0f - w) + b.z * w;
    r.w = a.w * (1.0f - w) + b.w * w;
    o[c] = r;
}

// ---------------------------------------------------------------------------
extern "C" void kernel_launch(void* const* d_in, const int* in_sizes, int n_in,
                              void* d_out, int out_size, void* d_ws, size_t ws_size,
                              hipStream_t stream)
{
    (void)in_sizes; (void)n_in; (void)ws_size; (void)out_size;
    const float* query    = (const float*)d_in[0];
    const float* key      = (const float*)d_in[1];
    const float* value    = (const float*)d_in[2];
    const float* strat    = (const float*)d_in[3];
    const float* Wqkv_lin = (const float*)d_in[4];
    const float* b_lin    = (const float*)d_in[5];
    const float* Wo_lin   = (const float*)d_in[6];
    const float* bo_lin   = (const float*)d_in[7];
    const float* spars    = (const float*)d_in[8];
    const float* Wqkv_loc = (const float*)d_in[9];
    const float* b_loc    = (const float*)d_in[10];
    const float* Wo_loc   = (const float*)d_in[11];
    const float* bo_loc   = (const float*)d_in[12];
    const float* Wqkv_glb = (const float*)d_in[13];
    const float* b_glb    = (const float*)d_in[14];
    const float* Wo_glb   = (const float*)d_in[15];
    const float* bo_glb   = (const float*)d_in[16];
    const float* Wf       = (const float*)d_in[17];
    const float* bf       = (const float*)d_in[18];
    const float* Rq       = (const float*)d_in[19];
    const float* ent      = (const float*)d_in[20];

    float* out = (float*)d_out;
    float* weighted = out;                        // [2048][1024]
    float* combined = out + (size_t)2048 * 1024;  // [3][2048][2048]
    const size_t PLANE = (size_t)2048 * 2048;

    float* ws   = (float*)d_ws;
    float* qkv  = ws;                   // 3 x 2048x1024
    float* AO   = qkv + 6291456;
    float* LO   = AO + 2097152;
    float* gqkv = LO + 2097152;
    float* gAO  = gqkv + 786432;
    float* gOUT = gAO + 262144;
    float* GI   = gOUT + 262144;
    float* mb   = GI + 2097152;
    float* lb   = mb + 32768;
    float* qrot = qkv;                  // alias: lin qkv dead by then
    float* krot = qkv + 2097152;

    const float inv8   = 0.125f;
    const float inv128 = 1.0f / sqrtf(128.0f);
    const float* srcs[3] = {query, key, value};

    // zero only weighted (combined fully overwritten by comb_plane)
    hipMemsetAsync(weighted, 0, (size_t)2097152 * sizeof(float), stream);

    // ---- LINEAR (proj'd MHA, 16 heads; combined plane 0) ----
    for (int sl = 0; sl < 3; ++sl)
        gemm_xwt<<<dim3(32, 16), 256, 0, stream>>>(
            srcs[sl], 1024, Wqkv_lin + (size_t)sl * 1048576, 1024, b_lin + sl * 1024,
            qkv + (size_t)sl * 2097152, 2048, 1024, 1024, nullptr, 0, 0);
    flash_attn<64><<<dim3(32, 16), 256, 0, stream>>>(
        qkv, qkv + 2097152, qkv + 4194304, nullptr, 0,
        AO, strat, -1, 0, mb, lb, 2048, 2048, inv8);
    comb_plane<<<dim3(32, 16), 256, 0, stream>>>(
        qkv, qkv + 2097152, mb, lb, nullptr, 0, strat,
        combined + 0 * PLANE, 2048, 2048, 16, inv8);
    gemm_xwt<<<dim3(32, 16), 256, 0, stream>>>(
        AO, 1024, Wo_lin, 1024, bo_lin, weighted, 2048, 1024, 1024, strat, 0, 1);

    // ---- SPARSE (raw heads, per-head mask; combined plane 1) ----
    flash_attn<64><<<dim3(32, 16), 256, 0, stream>>>(
        query, key, value, spars, 1,
        weighted, strat, 1, 1, mb, lb, 2048, 2048, inv8);
    comb_plane<<<dim3(32, 16), 256, 0, stream>>>(
        query, key, mb, lb, spars, 1, strat,
        combined + 1 * PLANE, 2048, 2048, 16, inv8);

    // ---- QUANTUM (rotated raw heads, per-head gate; combined plane 2) ----
    rotate_heads<<<dim3(32, 16), 256, 0, stream>>>(query, Rq, qrot);
    rotate_heads<<<dim3(32, 16), 256, 0, stream>>>(key, Rq, krot);
    flash_attn<64><<<dim3(32, 16), 256, 0, stream>>>(
        qrot, krot, value, ent, 2,
        weighted, strat, 3, 1, mb, lb, 2048, 2048, inv8);
    comb_plane<<<dim3(32, 16), 256, 0, stream>>>(
        qrot, krot, mb, lb, ent, 2, strat,
        combined + 2 * PLANE, 2048, 2048, 16, inv8);

    // ---- LOCAL (proj'd MHA, 8 heads x 128) ----
    for (int sl = 0; sl < 3; ++sl)
        gemm_xwt<<<dim3(32, 16), 256, 0, stream>>>(
            srcs[sl], 1024, Wqkv_loc + (size_t)sl * 1048576, 1024, b_loc + sl * 1024,
            qkv + (size_t)sl * 2097152, 2048, 1024, 1024, nullptr, 0, 0);
    flash_attn<128><<<dim3(32, 8), 256, 0, stream>>>(
        qkv, qkv + 2097152, qkv + 4194304, nullptr, 0,
        AO, strat, -1, 0, mb, lb, 2048, 2048, inv128);
    gemm_xwt<<<dim3(32, 16), 256, 0, stream>>>(
        AO, 1024, Wo_loc, 1024, bo_loc, LO, 2048, 1024, 1024, nullptr, 0, 0);

    // ---- GLOBAL (strided pool to 256 tokens, 8 heads x 128, interp back) ----
    for (int sl = 0; sl < 3; ++sl)
        gemm_xwt<<<dim3(4, 16), 256, 0, stream>>>(
            srcs[sl], 8192, Wqkv_glb + (size_t)sl * 1048576, 1024, b_glb + sl * 1024,
            gqkv + (size_t)sl * 262144, 256, 1024, 1024, nullptr, 0, 0);
    flash_attn<128><<<dim3(4, 8), 256, 0, stream>>>(
        gqkv, gqkv + 262144, gqkv + 524288, nullptr, 0,
        gAO, strat, -1, 0, mb, lb, 256, 256, inv128);
    gemm_xwt<<<dim3(4, 16), 256, 0, stream>>>(
        gAO, 1024, Wo_glb, 1024, bo_glb, gOUT, 256, 1024, 1024, nullptr, 0, 0);
    interp_lin<<<dim3(2048), 256, 0, stream>>>(gOUT, GI);

    // ---- HIER: weighted += s2 * (LO @ WfL^T + GI @ WfR^T + bf) ----
    gemm_xwt<<<dim3(32, 16), 256, 0, stream>>>(
        LO, 1024, Wf, 2048, bf, weighted, 2048, 1024, 1024, strat, 2, 1);
    gemm_xwt<<<dim3(32, 16), 256, 0, stream>>>(
        GI, 1024, Wf + 1024, 2048, nullptr, weighted, 2048, 1024, 1024, strat, 2, 1);
}

// Round 4
// 7387.450 us; speedup vs baseline: 1.5648x; 1.5648x over previous
//
#include <hip/hip_runtime.h>
#include <math.h>

// Problem constants: B=1, T=2048, D=1024, H=16, HD=64, STRIDE=8, Tg=256.
// Output 0: weighted [2048][1024]
// Output 1: combined [3][2048][2048] = (s0+s1+s3) * {linear_w, sparse_w, quantum_w}
#define D_MODEL 1024

// ---------------------------------------------------------------------------
// GEMM: C[M,N] (+)= scale * (X[M,K] @ W[N,K]^T + bias)
// ---------------------------------------------------------------------------
__global__ __launch_bounds__(256) void gemm_xwt(
    const float* __restrict__ X, int xrstride,
    const float* __restrict__ W, int wrstride,
    const float* __restrict__ bias,
    float* __restrict__ C, int M, int N, int K,
    const float* __restrict__ sptr, int sidx, int accum)
{
    __shared__ float Xs[16][68];
    __shared__ float Ws[16][68];
    const int tid = threadIdx.x;
    const int m0 = blockIdx.x * 64, n0 = blockIdx.y * 64;
    const int ty = tid >> 4, tx = tid & 15;
    float acc[4][4] = {};
    for (int k0 = 0; k0 < K; k0 += 16) {
        __syncthreads();
#pragma unroll
        for (int i = 0; i < 4; ++i) {
            int li = tid + i * 256;
            int r = li >> 4, kk = li & 15;
            Xs[kk][r] = X[(size_t)(m0 + r) * xrstride + k0 + kk];
            Ws[kk][r] = W[(size_t)(n0 + r) * wrstride + k0 + kk];
        }
        __syncthreads();
#pragma unroll
        for (int kk = 0; kk < 16; ++kk) {
            float4 a4 = *(const float4*)&Xs[kk][ty * 4];
            float4 b4 = *(const float4*)&Ws[kk][tx * 4];
            float av[4] = {a4.x, a4.y, a4.z, a4.w};
            float bv[4] = {b4.x, b4.y, b4.z, b4.w};
#pragma unroll
            for (int i = 0; i < 4; ++i)
#pragma unroll
                for (int j = 0; j < 4; ++j)
                    acc[i][j] += av[i] * bv[j];
        }
    }
    const float s = (sptr != nullptr) ? sptr[sidx] : 1.0f;
#pragma unroll
    for (int i = 0; i < 4; ++i) {
        const size_t row = (size_t)(m0 + ty * 4 + i) * N;
#pragma unroll
        for (int j = 0; j < 4; ++j) {
            const int col = n0 + tx * 4 + j;
            float v = acc[i][j] + (bias ? bias[col] : 0.0f);
            if (accum) C[row + col] += s * v;
            else       C[row + col]  = s * v;
        }
    }
}

// ---------------------------------------------------------------------------
// alpha: amode 0 -> 1; amode 1 -> mask (sigmoid>0.5 <=> x>0); amode 2 -> gate
// ---------------------------------------------------------------------------
__device__ __forceinline__ float head_alpha(const float* ap, int amode, int h) {
    if (amode == 1) return (ap[h] > 0.0f) ? 1.0f : 0.0f;
    if (amode == 2) return 1.0f / (1.0f + __expf(-ap[h * 4]));
    return 1.0f;
}

// ---------------------------------------------------------------------------
// Single-pass flash attention, one block = (head, 64 query rows).
//   O (+)= osc * softmax(ascale * Q K^T) V, written exactly once (no atomics)
//   m,l row stats written for later comb_plane use.
//   Masked heads (amode 1, alpha=0): p uniform -> skip QK/softmax, O=mean(V).
// NOTE: PV s-loop MUST stay "#pragma unroll 4" — full unroll spilled to
// scratch (VGPR 256, ~10 GB phantom scratch traffic, 6 ms/dispatch in r3).
// ---------------------------------------------------------------------------
template <int HD>
__global__ __launch_bounds__(256) void flash_attn(
    const float* __restrict__ Q, const float* __restrict__ K,
    const float* __restrict__ V,
    const float* __restrict__ aparam, int amode,
    float* __restrict__ O,
    const float* __restrict__ strat, int o_sidx, int accum,
    float* __restrict__ mout, float* __restrict__ lout,
    int Tq, int Tk, float inv_scale)
{
    constexpr int ROWS = 64;
    constexpr int STILE = (HD == 64) ? 64 : 32;
    constexpr int CPT = STILE / 16;   // score cols per thread
    constexpr int PC = HD / 4;        // PV cols per thread
    __shared__ float qs[ROWS][HD + 4];
    __shared__ float ks[STILE][HD + 4];
    __shared__ float ptile[ROWS][STILE + 1];
    __shared__ float alpha_s[ROWS];
    __shared__ float linv_s[ROWS];

    const int tid = threadIdx.x;
    const int h = blockIdx.y;
    const int r0 = blockIdx.x * ROWS;
    const float ascale = head_alpha(aparam, amode, h) * inv_scale;
    const bool masked = (amode == 1) && (ascale == 0.0f);

    for (int idx = tid; idx < ROWS * HD; idx += 256) {
        int r = idx / HD, d = idx % HD;
        qs[r][d] = Q[(size_t)(r0 + r) * D_MODEL + h * HD + d];
    }
    const int ty = tid >> 4, tx = tid & 15;   // score mapping: rows ty*4+i, cols tx+16*j
    const int pr = tid >> 2, pc0 = (tid & 3) * PC;  // PV mapping

    float mreg[4], lreg[4];
#pragma unroll
    for (int i = 0; i < 4; ++i) { mreg[i] = -1e30f; lreg[i] = 0.0f; }
    float4 oacc[PC / 4];
#pragma unroll
    for (int j = 0; j < PC / 4; ++j) oacc[j] = make_float4(0.f, 0.f, 0.f, 0.f);

    for (int s0 = 0; s0 < Tk; s0 += STILE) {
        if (!masked) {
            for (int idx = tid; idx < STILE * HD; idx += 256) {
                int r = idx / HD, d = idx % HD;
                ks[r][d] = K[(size_t)(s0 + r) * D_MODEL + h * HD + d];
            }
        }
        __syncthreads();
        if (!masked) {
            float sc[4][CPT];
#pragma unroll
            for (int i = 0; i < 4; ++i)
#pragma unroll
                for (int j = 0; j < CPT; ++j) sc[i][j] = 0.0f;
#pragma unroll 4
            for (int d0 = 0; d0 < HD; d0 += 4) {
                float4 bv[CPT];
#pragma unroll
                for (int j = 0; j < CPT; ++j) bv[j] = *(const float4*)&ks[tx + 16 * j][d0];
#pragma unroll
                for (int i = 0; i < 4; ++i) {
                    float4 a = *(const float4*)&qs[ty * 4 + i][d0];
#pragma unroll
                    for (int j = 0; j < CPT; ++j)
                        sc[i][j] += a.x * bv[j].x + a.y * bv[j].y + a.z * bv[j].z + a.w * bv[j].w;
                }
            }
#pragma unroll
            for (int i = 0; i < 4; ++i) {
                float tm = -1e30f;
#pragma unroll
                for (int j = 0; j < CPT; ++j) { sc[i][j] *= ascale; tm = fmaxf(tm, sc[i][j]); }
#pragma unroll
                for (int off = 1; off < 16; off <<= 1) tm = fmaxf(tm, __shfl_xor(tm, off));
                float nm = fmaxf(mreg[i], tm);
                float pj[CPT];
                float ps = 0.0f;
#pragma unroll
                for (int j = 0; j < CPT; ++j) { pj[j] = __expf(sc[i][j] - nm); ps += pj[j]; }
#pragma unroll
                for (int off = 1; off < 16; off <<= 1) ps += __shfl_xor(ps, off);
                float al = __expf(mreg[i] - nm);
                lreg[i] = lreg[i] * al + ps;
                mreg[i] = nm;
#pragma unroll
                for (int j = 0; j < CPT; ++j) ptile[ty * 4 + i][tx + 16 * j] = pj[j];
                if (tx == 0) alpha_s[ty * 4 + i] = al;
            }
        }
        __syncthreads();
        // PV
        const float arow = masked ? 1.0f : alpha_s[pr];
#pragma unroll
        for (int jj = 0; jj < PC / 4; ++jj) {
            oacc[jj].x *= arow; oacc[jj].y *= arow;
            oacc[jj].z *= arow; oacc[jj].w *= arow;
        }
#pragma unroll 4
        for (int s = 0; s < STILE; ++s) {
            float p = masked ? 1.0f : ptile[pr][s];
            const float4* vr = (const float4*)(V + (size_t)(s0 + s) * D_MODEL + h * HD + pc0);
#pragma unroll
            for (int jj = 0; jj < PC / 4; ++jj) {
                float4 v4 = vr[jj];
                oacc[jj].x += p * v4.x; oacc[jj].y += p * v4.y;
                oacc[jj].z += p * v4.z; oacc[jj].w += p * v4.w;
            }
        }
    }
    // epilogue: stats out + normalized O write (once)
    if (tx == 0) {
#pragma unroll
        for (int i = 0; i < 4; ++i) {
            int r = ty * 4 + i;
            float lf = masked ? (float)Tk : lreg[i];
            mout[h * Tq + r0 + r] = masked ? 0.0f : mreg[i];
            lout[h * Tq + r0 + r] = lf;
            linv_s[r] = 1.0f / lf;
        }
    }
    __syncthreads();
    const float inv = linv_s[pr];
    const float osc = ((o_sidx >= 0) ? strat[o_sidx] : 1.0f) * inv;
    float4* orow = (float4*)(O + (size_t)(r0 + pr) * D_MODEL + h * HD + pc0);
#pragma unroll
    for (int jj = 0; jj < PC / 4; ++jj) {
        float4 v;
        v.x = osc * oacc[jj].x; v.y = osc * oacc[jj].y;
        v.z = osc * oacc[jj].z; v.w = osc * oacc[jj].w;
        if (accum) {
            float4 old = orow[jj];
            v.x += old.x; v.y += old.y; v.z += old.z; v.w += old.w;
        }
        orow[jj] = v;
    }
}

// ---------------------------------------------------------------------------
// comb plane: comb[r][c] = csc * sum_h exp(ascale*q_h.k_h - m)/l
// Block = 64 rows x 128 cols; loops all 16 heads (HD=64 only). One store per
// element, no RMW. Masked heads contribute exact uniform 1/Tk.
// ---------------------------------------------------------------------------
__global__ __launch_bounds__(256) void comb_plane(
    const float* __restrict__ Q, const float* __restrict__ K,
    const float* __restrict__ mrow, const float* __restrict__ lrow,
    const float* __restrict__ aparam, int amode,
    const float* __restrict__ strat,
    float* __restrict__ comb, int Tq, int Tk, int nh, float inv_scale)
{
    __shared__ float qs[64][68];
    __shared__ float ks[128][68];
    __shared__ float mls[64][2];
    const int tid = threadIdx.x;
    const int r0 = blockIdx.x * 64, c0 = blockIdx.y * 128;
    const int ty = tid >> 4, tx = tid & 15;   // rows ty*4+i, cols tx+16*j
    float acc[4][8] = {};
    float unif = 0.0f;
    for (int h = 0; h < nh; ++h) {
        const float ascale = head_alpha(aparam, amode, h) * inv_scale;
        if (amode == 1 && ascale == 0.0f) { unif += 1.0f; continue; }
        for (int idx = tid; idx < 64 * 64; idx += 256) {
            int r = idx >> 6, d = idx & 63;
            qs[r][d] = Q[(size_t)(r0 + r) * D_MODEL + h * 64 + d];
        }
        for (int idx = tid; idx < 128 * 64; idx += 256) {
            int r = idx >> 6, d = idx & 63;
            ks[r][d] = K[(size_t)(c0 + r) * D_MODEL + h * 64 + d];
        }
        if (tid < 64) {
            mls[tid][0] = mrow[h * Tq + r0 + tid];
            mls[tid][1] = 1.0f / lrow[h * Tq + r0 + tid];
        }
        __syncthreads();
        float sc[4][8] = {};
#pragma unroll 4
        for (int d0 = 0; d0 < 64; d0 += 4) {
            float4 bv[8];
#pragma unroll
            for (int j = 0; j < 8; ++j) bv[j] = *(const float4*)&ks[tx + 16 * j][d0];
#pragma unroll
            for (int i = 0; i < 4; ++i) {
                float4 a = *(const float4*)&qs[ty * 4 + i][d0];
#pragma unroll
                for (int j = 0; j < 8; ++j)
                    sc[i][j] += a.x * bv[j].x + a.y * bv[j].y + a.z * bv[j].z + a.w * bv[j].w;
            }
        }
#pragma unroll
        for (int i = 0; i < 4; ++i) {
            const float mm = mls[ty * 4 + i][0], li = mls[ty * 4 + i][1];
#pragma unroll
            for (int j = 0; j < 8; ++j)
                acc[i][j] += __expf(sc[i][j] * ascale - mm) * li;
        }
        __syncthreads();
    }
    const float csc = (strat[0] + strat[1] + strat[3]) / (float)nh;
    const float uadd = unif / (float)Tk;
#pragma unroll
    for (int i = 0; i < 4; ++i) {
        float* crow = comb + (size_t)(r0 + ty * 4 + i) * Tk + c0 + tx;
#pragma unroll
        for (int j = 0; j < 8; ++j)
            crow[16 * j] = csc * (acc[i][j] + uadd);
    }
}

// ---------------------------------------------------------------------------
// Per-head 64x64 rotation: Y[t][h*64+e] = sum_d X[t][h*64+d] * R[h][d][e]
// ---------------------------------------------------------------------------
__global__ __launch_bounds__(256) void rotate_heads(
    const float* __restrict__ X, const float* __restrict__ R,
    float* __restrict__ Y)
{
    __shared__ float Rt[64][68];
    __shared__ float xs[64][68];
    const int tid = threadIdx.x;
    const int h = blockIdx.y;
    const int t0 = blockIdx.x * 64;
    for (int idx = tid; idx < 4096; idx += 256) {
        int d = idx >> 6, e = idx & 63;
        Rt[e][d] = R[h * 4096 + idx];
        xs[d][e] = X[(size_t)(t0 + d) * D_MODEL + h * 64 + e];
    }
    __syncthreads();
    const int ty = tid >> 4, tx = tid & 15;
    float acc[4][4] = {};
#pragma unroll 4
    for (int d0 = 0; d0 < 64; d0 += 4) {
        float4 rv[4];
#pragma unroll
        for (int j = 0; j < 4; ++j) rv[j] = *(const float4*)&Rt[tx * 4 + j][d0];
#pragma unroll
        for (int i = 0; i < 4; ++i) {
            float4 a = *(const float4*)&xs[ty * 4 + i][d0];
#pragma unroll
            for (int j = 0; j < 4; ++j)
                acc[i][j] += a.x * rv[j].x + a.y * rv[j].y + a.z * rv[j].z + a.w * rv[j].w;
        }
    }
#pragma unroll
    for (int i = 0; i < 4; ++i)
#pragma unroll
        for (int j = 0; j < 4; ++j)
            Y[(size_t)(t0 + ty * 4 + i) * D_MODEL + h * 64 + tx * 4 + j] = acc[i][j];
}

// ---------------------------------------------------------------------------
// F.interpolate(mode='linear', align_corners=False): [256,1024] -> [2048,1024]
// ---------------------------------------------------------------------------
__global__ __launch_bounds__(256) void interp_lin(
    const float* __restrict__ G, float* __restrict__ out)
{
    const int t = blockIdx.x;
    float src = (t + 0.5f) * 0.125f - 0.5f;
    src = fminf(fmaxf(src, 0.0f), 255.0f);
    float fl = floorf(src);
    int i0 = (int)fl;
    int i1 = min(i0 + 1, 255);
    float w = src - fl;
    const float4* g0 = (const float4*)(G + (size_t)i0 * D_MODEL);
    const float4* g1 = (const float4*)(G + (size_t)i1 * D_MODEL);
    float4* o = (float4*)(out + (size_t)t * D_MODEL);
    int c = threadIdx.x;
    float4 a = g0[c], b = g1[c];
    float4 r;
    r.x = a.x * (1.0f - w) + b.x * w;
    r.y = a.y * (1.0f - w) + b.y * w;
    r.z = a.z * (1.0f - w) + b.z * w;
    r.w = a.w * (1.0f - w) + b.w * w;
    o[c] = r;
}

// ---------------------------------------------------------------------------
extern "C" void kernel_launch(void* const* d_in, const int* in_sizes, int n_in,
                              void* d_out, int out_size, void* d_ws, size_t ws_size,
                              hipStream_t stream)
{
    (void)in_sizes; (void)n_in; (void)ws_size; (void)out_size;
    const float* query    = (const float*)d_in[0];
    const float* key      = (const float*)d_in[1];
    const float* value    = (const float*)d_in[2];
    const float* strat    = (const float*)d_in[3];
    const float* Wqkv_lin = (const float*)d_in[4];
    const float* b_lin    = (const float*)d_in[5];
    const float* Wo_lin   = (const float*)d_in[6];
    const float* bo_lin   = (const float*)d_in[7];
    const float* spars    = (const float*)d_in[8];
    const float* Wqkv_loc = (const float*)d_in[9];
    const float* b_loc    = (const float*)d_in[10];
    const float* Wo_loc   = (const float*)d_in[11];
    const float* bo_loc   = (const float*)d_in[12];
    const float* Wqkv_glb = (const float*)d_in[13];
    const float* b_glb    = (const float*)d_in[14];
    const float* Wo_glb   = (const float*)d_in[15];
    const float* bo_glb   = (const float*)d_in[16];
    const float* Wf       = (const float*)d_in[17];
    const float* bf       = (const float*)d_in[18];
    const float* Rq       = (const float*)d_in[19];
    const float* ent      = (const float*)d_in[20];

    float* out = (float*)d_out;
    float* weighted = out;                        // [2048][1024]
    float* combined = out + (size_t)2048 * 1024;  // [3][2048][2048]
    const size_t PLANE = (size_t)2048 * 2048;

    float* ws   = (float*)d_ws;
    float* qkv  = ws;                   // 3 x 2048x1024
    float* AO   = qkv + 6291456;
    float* LO   = AO + 2097152;
    float* gqkv = LO + 2097152;
    float* gAO  = gqkv + 786432;
    float* gOUT = gAO + 262144;
    float* GI   = gOUT + 262144;
    float* mb   = GI + 2097152;
    float* lb   = mb + 32768;
    float* qrot = qkv;                  // alias: lin qkv dead by then
    float* krot = qkv + 2097152;

    const float inv8   = 0.125f;
    const float inv128 = 1.0f / sqrtf(128.0f);
    const float* srcs[3] = {query, key, value};

    // zero only weighted (combined fully overwritten by comb_plane)
    hipMemsetAsync(weighted, 0, (size_t)2097152 * sizeof(float), stream);

    // ---- LINEAR (proj'd MHA, 16 heads; combined plane 0) ----
    for (int sl = 0; sl < 3; ++sl)
        gemm_xwt<<<dim3(32, 16), 256, 0, stream>>>(
            srcs[sl], 1024, Wqkv_lin + (size_t)sl * 1048576, 1024, b_lin + sl * 1024,
            qkv + (size_t)sl * 2097152, 2048, 1024, 1024, nullptr, 0, 0);
    flash_attn<64><<<dim3(32, 16), 256, 0, stream>>>(
        qkv, qkv + 2097152, qkv + 4194304, nullptr, 0,
        AO, strat, -1, 0, mb, lb, 2048, 2048, inv8);
    comb_plane<<<dim3(32, 16), 256, 0, stream>>>(
        qkv, qkv + 2097152, mb, lb, nullptr, 0, strat,
        combined + 0 * PLANE, 2048, 2048, 16, inv8);
    gemm_xwt<<<dim3(32, 16), 256, 0, stream>>>(
        AO, 1024, Wo_lin, 1024, bo_lin, weighted, 2048, 1024, 1024, strat, 0, 1);

    // ---- SPARSE (raw heads, per-head mask; combined plane 1) ----
    flash_attn<64><<<dim3(32, 16), 256, 0, stream>>>(
        query, key, value, spars, 1,
        weighted, strat, 1, 1, mb, lb, 2048, 2048, inv8);
    comb_plane<<<dim3(32, 16), 256, 0, stream>>>(
        query, key, mb, lb, spars, 1, strat,
        combined + 1 * PLANE, 2048, 2048, 16, inv8);

    // ---- QUANTUM (rotated raw heads, per-head gate; combined plane 2) ----
    rotate_heads<<<dim3(32, 16), 256, 0, stream>>>(query, Rq, qrot);
    rotate_heads<<<dim3(32, 16), 256, 0, stream>>>(key, Rq, krot);
    flash_attn<64><<<dim3(32, 16), 256, 0, stream>>>(
        qrot, krot, value, ent, 2,
        weighted, strat, 3, 1, mb, lb, 2048, 2048, inv8);
    comb_plane<<<dim3(32, 16), 256, 0, stream>>>(
        qrot, krot, mb, lb, ent, 2, strat,
        combined + 2 * PLANE, 2048, 2048, 16, inv8);

    // ---- LOCAL (proj'd MHA, 8 heads x 128) ----
    for (int sl = 0; sl < 3; ++sl)
        gemm_xwt<<<dim3(32, 16), 256, 0, stream>>>(
            srcs[sl], 1024, Wqkv_loc + (size_t)sl * 1048576, 1024, b_loc + sl * 1024,
            qkv + (size_t)sl * 2097152, 2048, 1024, 1024, nullptr, 0, 0);
    flash_attn<128><<<dim3(32, 8), 256, 0, stream>>>(
        qkv, qkv + 2097152, qkv + 4194304, nullptr, 0,
        AO, strat, -1, 0, mb, lb, 2048, 2048, inv128);
    gemm_xwt<<<dim3(32, 16), 256, 0, stream>>>(
        AO, 1024, Wo_loc, 1024, bo_loc, LO, 2048, 1024, 1024, nullptr, 0, 0);

    // ---- GLOBAL (strided pool to 256 tokens, 8 heads x 128, interp back) ----
    for (int sl = 0; sl < 3; ++sl)
        gemm_xwt<<<dim3(4, 16), 256, 0, stream>>>(
            srcs[sl], 8192, Wqkv_glb + (size_t)sl * 1048576, 1024, b_glb + sl * 1024,
            gqkv + (size_t)sl * 262144, 256, 1024, 1024, nullptr, 0, 0);
    flash_attn<128><<<dim3(4, 8), 256, 0, stream>>>(
        gqkv, gqkv + 262144, gqkv + 524288, nullptr, 0,
        gAO, strat, -1, 0, mb, lb, 256, 256, inv128);
    gemm_xwt<<<dim3(4, 16), 256, 0, stream>>>(
        gAO, 1024, Wo_glb, 1024, bo_glb, gOUT, 256, 1024, 1024, nullptr, 0, 0);
    interp_lin<<<dim3(2048), 256, 0, stream>>>(gOUT, GI);

    // ---- HIER: weighted += s2 * (LO @ WfL^T + GI @ WfR^T + bf) ----
    gemm_xwt<<<dim3(32, 16), 256, 0, stream>>>(
        LO, 1024, Wf, 2048, bf, weighted, 2048, 1024, 1024, strat, 2, 1);
    gemm_xwt<<<dim3(32, 16), 256, 0, stream>>>(
        GI, 1024, Wf + 1024, 2048, nullptr, weighted, 2048, 1024, 1024, strat, 2, 1);
}

// Round 5
// 2370.121 us; speedup vs baseline: 4.8773x; 3.1169x over previous
//
#include <hip/hip_runtime.h>
#include <math.h>

// Problem constants: B=1, T=2048, D=1024, H=16, HD=64, STRIDE=8, Tg=256.
// Output 0: weighted [2048][1024]
// Output 1: combined [3][2048][2048] = (s0+s1+s3) * {linear_w, sparse_w, quantum_w}
#define D_MODEL 1024

typedef __attribute__((ext_vector_type(8))) short bf16x8;
typedef __attribute__((ext_vector_type(4))) float f32x4;

// fp32 -> bf16 RNE, and bf16 -> fp32
__device__ __forceinline__ unsigned short bfr(float f) {
    unsigned u = __float_as_uint(f);
    u += 0x7fffu + ((u >> 16) & 1u);
    return (unsigned short)(u >> 16);
}
__device__ __forceinline__ float bff(unsigned short s) {
    return __uint_as_float(((unsigned)s) << 16);
}
// split x = hi + lo (both bf16); hi*hi+hi*lo+lo*hi captures x*y to ~2^-17 rel
__device__ __forceinline__ void split2(float x, unsigned short &h, unsigned short &l) {
    h = bfr(x);
    l = bfr(x - bff(h));
}
__device__ __forceinline__ f32x4 mfma3(bf16x8 ah, bf16x8 al, bf16x8 bh, bf16x8 bl, f32x4 c) {
    c = __builtin_amdgcn_mfma_f32_16x16x32_bf16(ah, bh, c, 0, 0, 0);
    c = __builtin_amdgcn_mfma_f32_16x16x32_bf16(ah, bl, c, 0, 0, 0);
    c = __builtin_amdgcn_mfma_f32_16x16x32_bf16(al, bh, c, 0, 0, 0);
    return c;
}

// ---------------------------------------------------------------------------
// MFMA GEMM: C[M,N] (+)= scale * (X[M,K] @ W[N,K]^T + bias), split-bf16.
// 64x64 tile, 4 waves (wave = 16-row m-block x 64 cols), K-step 32.
// ---------------------------------------------------------------------------
__global__ __launch_bounds__(256) void gemm_mfma(
    const float* __restrict__ X, int xrstride,
    const float* __restrict__ W, int wrstride,
    const float* __restrict__ bias,
    float* __restrict__ C, int M, int N, int K,
    const float* __restrict__ sptr, int sidx, int accum)
{
    __shared__ unsigned short Xh[64][40], Xl[64][40];
    __shared__ unsigned short Wh[64][40], Wl[64][40];
    const int tid = threadIdx.x;
    const int m0 = blockIdx.x * 64, n0 = blockIdx.y * 64;
    const int lane = tid & 63, wave = tid >> 6;
    const int c = lane & 15, quad = lane >> 4;
    const int mbase = wave * 16;

    f32x4 acc[4];
#pragma unroll
    for (int nt = 0; nt < 4; ++nt) acc[nt] = (f32x4){0.f, 0.f, 0.f, 0.f};

    for (int k0 = 0; k0 < K; k0 += 32) {
        __syncthreads();
#pragma unroll
        for (int it = 0; it < 2; ++it) {
            int idx = tid + it * 256;           // 512 float4 for X
            int r = idx >> 3, d4 = (idx & 7) * 4;
            float4 v = *(const float4*)&X[(size_t)(m0 + r) * xrstride + k0 + d4];
            ushort4 hs, ls;
            split2(v.x, hs.x, ls.x); split2(v.y, hs.y, ls.y);
            split2(v.z, hs.z, ls.z); split2(v.w, hs.w, ls.w);
            *(ushort4*)&Xh[r][d4] = hs; *(ushort4*)&Xl[r][d4] = ls;
        }
#pragma unroll
        for (int it = 0; it < 2; ++it) {
            int idx = tid + it * 256;           // 512 float4 for W
            int r = idx >> 3, d4 = (idx & 7) * 4;
            float4 v = *(const float4*)&W[(size_t)(n0 + r) * wrstride + k0 + d4];
            ushort4 hs, ls;
            split2(v.x, hs.x, ls.x); split2(v.y, hs.y, ls.y);
            split2(v.z, hs.z, ls.z); split2(v.w, hs.w, ls.w);
            *(ushort4*)&Wh[r][d4] = hs; *(ushort4*)&Wl[r][d4] = ls;
        }
        __syncthreads();
        bf16x8 ah = *(const bf16x8*)&Xh[mbase + c][quad * 8];
        bf16x8 al = *(const bf16x8*)&Xl[mbase + c][quad * 8];
#pragma unroll
        for (int nt = 0; nt < 4; ++nt) {
            bf16x8 bh = *(const bf16x8*)&Wh[nt * 16 + c][quad * 8];
            bf16x8 bl = *(const bf16x8*)&Wl[nt * 16 + c][quad * 8];
            acc[nt] = mfma3(ah, al, bh, bl, acc[nt]);
        }
    }
    const float s = (sptr != nullptr) ? sptr[sidx] : 1.0f;
#pragma unroll
    for (int nt = 0; nt < 4; ++nt) {
#pragma unroll
        for (int reg = 0; reg < 4; ++reg) {
            int row = m0 + mbase + quad * 4 + reg;
            int col = n0 + nt * 16 + c;
            float v = acc[nt][reg] + (bias ? bias[col] : 0.0f);
            v *= s;
            size_t gi = (size_t)row * N + col;
            if (accum) v += C[gi];
            C[gi] = v;
        }
    }
}

// ---------------------------------------------------------------------------
// MFMA flash attention, one block = (head, 64 query rows), split-bf16.
//   O (+)= osc * softmax(ascale * Q K^T) V, single O write; m,l emitted.
//   Fragment layouts (verified, guide §3): A[m=lane&15][k=quad*8+j],
//   B[k=quad*8+j][n=lane&15], C/D col=lane&15 row=quad*4+reg.
//   S and O fragments share the row mapping -> online-softmax alpha stays
//   in registers. P round-trips LDS (C/D layout -> A layout).
//   Masked heads (amode 1, gate 0): P==1, l=Tk, m=0 (exact uniform).
// ---------------------------------------------------------------------------
template <int HD>
__global__ __launch_bounds__(256) void flash_mfma(
    const float* __restrict__ Q, const float* __restrict__ K,
    const float* __restrict__ V,
    const float* __restrict__ aparam, int amode,
    float* __restrict__ O,
    const float* __restrict__ strat, int o_sidx, int accum,
    float* __restrict__ mout, float* __restrict__ lout,
    int Tq, int Tk, float inv_scale)
{
    constexpr int ROWS = 64;
    constexpr int STILE = (HD == 64) ? 64 : 32;
    constexpr int NT_S = STILE / 16;   // score n-tiles
    constexpr int KS   = HD / 32;      // QK k-steps
    constexpr int NT_O = HD / 16;      // O n-tiles
    constexpr int KS_PV = STILE / 32;  // PV k-steps
    constexpr int QP = HD + 8;         // padded row length (u16), 16B-aligned
    constexpr int SP = STILE + 8;

    __shared__ unsigned short Qh[ROWS][QP], Ql[ROWS][QP];
    __shared__ unsigned short Kh[STILE][QP], Kl[STILE][QP];
    __shared__ unsigned short Ph[ROWS][SP], Pl[ROWS][SP];
    __shared__ unsigned short Vh[HD][SP],  Vl[HD][SP];

    const int tid = threadIdx.x;
    const int h = blockIdx.y;
    const int r0 = blockIdx.x * ROWS;
    const int lane = tid & 63, wave = tid >> 6;
    const int c = lane & 15, quad = lane >> 4;
    const int mbase = wave * 16;

    float gate = 1.0f;
    if (amode == 1) gate = (aparam[h] > 0.0f) ? 1.0f : 0.0f;
    if (amode == 2) gate = 1.0f / (1.0f + __expf(-aparam[h * 4]));
    const float ascale = gate * inv_scale;
    const bool masked = (amode == 1) && (gate == 0.0f);

    // stage Q (once)
    for (int idx = tid; idx < ROWS * HD / 4; idx += 256) {
        int r = idx / (HD / 4), d4 = (idx % (HD / 4)) * 4;
        float4 v = *(const float4*)&Q[(size_t)(r0 + r) * D_MODEL + h * HD + d4];
        ushort4 hs, ls;
        split2(v.x, hs.x, ls.x); split2(v.y, hs.y, ls.y);
        split2(v.z, hs.z, ls.z); split2(v.w, hs.w, ls.w);
        *(ushort4*)&Qh[r][d4] = hs; *(ushort4*)&Ql[r][d4] = ls;
    }
    if (masked) {  // uniform P == 1.0
        for (int idx = tid; idx < ROWS * STILE; idx += 256) {
            int r = idx / STILE, cc = idx % STILE;
            Ph[r][cc] = 0x3F80; Pl[r][cc] = 0;
        }
    }
    __syncthreads();

    // Q A-fragments are key-loop invariant: preload
    bf16x8 qah[KS], qal[KS];
#pragma unroll
    for (int ks = 0; ks < KS; ++ks) {
        qah[ks] = *(const bf16x8*)&Qh[mbase + c][ks * 32 + quad * 8];
        qal[ks] = *(const bf16x8*)&Ql[mbase + c][ks * 32 + quad * 8];
    }

    float mreg[4], lreg[4];
#pragma unroll
    for (int i = 0; i < 4; ++i) { mreg[i] = -1e30f; lreg[i] = 0.0f; }
    f32x4 oacc[NT_O];
#pragma unroll
    for (int nt = 0; nt < NT_O; ++nt) oacc[nt] = (f32x4){0.f, 0.f, 0.f, 0.f};

    for (int s0 = 0; s0 < Tk; s0 += STILE) {
        // stage K (skip if masked) and V (transposed) for this tile
        if (!masked) {
            for (int idx = tid; idx < STILE * HD / 4; idx += 256) {
                int r = idx / (HD / 4), d4 = (idx % (HD / 4)) * 4;
                float4 v = *(const float4*)&K[(size_t)(s0 + r) * D_MODEL + h * HD + d4];
                ushort4 hs, ls;
                split2(v.x, hs.x, ls.x); split2(v.y, hs.y, ls.y);
                split2(v.z, hs.z, ls.z); split2(v.w, hs.w, ls.w);
                *(ushort4*)&Kh[r][d4] = hs; *(ushort4*)&Kl[r][d4] = ls;
            }
        }
        for (int idx = tid; idx < STILE * HD / 4; idx += 256) {
            int s = idx / (HD / 4), d4 = (idx % (HD / 4)) * 4;
            float4 v = *(const float4*)&V[(size_t)(s0 + s) * D_MODEL + h * HD + d4];
            unsigned short hh, ll;
            split2(v.x, hh, ll); Vh[d4 + 0][s] = hh; Vl[d4 + 0][s] = ll;
            split2(v.y, hh, ll); Vh[d4 + 1][s] = hh; Vl[d4 + 1][s] = ll;
            split2(v.z, hh, ll); Vh[d4 + 2][s] = hh; Vl[d4 + 2][s] = ll;
            split2(v.w, hh, ll); Vh[d4 + 3][s] = hh; Vl[d4 + 3][s] = ll;
        }
        __syncthreads();

        float alpha[4] = {1.0f, 1.0f, 1.0f, 1.0f};
        if (!masked) {
            // scores for this wave's 16-row m-block, all STILE keys
            f32x4 sf[NT_S];
#pragma unroll
            for (int nt = 0; nt < NT_S; ++nt) {
                f32x4 s = (f32x4){0.f, 0.f, 0.f, 0.f};
#pragma unroll
                for (int ks = 0; ks < KS; ++ks) {
                    bf16x8 bh = *(const bf16x8*)&Kh[nt * 16 + c][ks * 32 + quad * 8];
                    bf16x8 bl = *(const bf16x8*)&Kl[nt * 16 + c][ks * 32 + quad * 8];
                    s = mfma3(qah[ks], qal[ks], bh, bl, s);
                }
                sf[nt] = s * ascale;
            }
            // row max (rows quad*4+reg; cols spread over 16 lanes of the quad)
            float tm[4] = {-1e30f, -1e30f, -1e30f, -1e30f};
#pragma unroll
            for (int nt = 0; nt < NT_S; ++nt)
#pragma unroll
                for (int reg = 0; reg < 4; ++reg) tm[reg] = fmaxf(tm[reg], sf[nt][reg]);
#pragma unroll
            for (int off = 1; off < 16; off <<= 1)
#pragma unroll
                for (int reg = 0; reg < 4; ++reg) tm[reg] = fmaxf(tm[reg], __shfl_xor(tm[reg], off));
            float ps[4] = {0.f, 0.f, 0.f, 0.f};
#pragma unroll
            for (int reg = 0; reg < 4; ++reg) {
                float nm = fmaxf(mreg[reg], tm[reg]);
                alpha[reg] = __expf(mreg[reg] - nm);
                mreg[reg] = nm;
            }
            // p = exp(s - m), store to LDS (hi/lo) for PV A-operand
#pragma unroll
            for (int nt = 0; nt < NT_S; ++nt) {
#pragma unroll
                for (int reg = 0; reg < 4; ++reg) {
                    float p = __expf(sf[nt][reg] - mreg[reg]);
                    ps[reg] += p;
                    unsigned short hh, ll;
                    split2(p, hh, ll);
                    int row = mbase + quad * 4 + reg;
                    Ph[row][nt * 16 + c] = hh;
                    Pl[row][nt * 16 + c] = ll;
                }
            }
#pragma unroll
            for (int off = 1; off < 16; off <<= 1)
#pragma unroll
                for (int reg = 0; reg < 4; ++reg) ps[reg] += __shfl_xor(ps[reg], off);
#pragma unroll
            for (int reg = 0; reg < 4; ++reg) lreg[reg] = lreg[reg] * alpha[reg] + ps[reg];
        }
        // PV: P rows of this m-block were written by this same wave (in-order
        // LDS within a wave); V staged before the barrier above.
        bf16x8 pah[KS_PV], pal[KS_PV];
#pragma unroll
        for (int ks = 0; ks < KS_PV; ++ks) {
            pah[ks] = *(const bf16x8*)&Ph[mbase + c][ks * 32 + quad * 8];
            pal[ks] = *(const bf16x8*)&Pl[mbase + c][ks * 32 + quad * 8];
        }
#pragma unroll
        for (int nt = 0; nt < NT_O; ++nt) {
            f32x4 o = oacc[nt];
#pragma unroll
            for (int reg = 0; reg < 4; ++reg) o[reg] *= alpha[reg];
#pragma unroll
            for (int ks = 0; ks < KS_PV; ++ks) {
                bf16x8 bh = *(const bf16x8*)&Vh[nt * 16 + c][ks * 32 + quad * 8];
                bf16x8 bl = *(const bf16x8*)&Vl[nt * 16 + c][ks * 32 + quad * 8];
                o = mfma3(pah[ks], pal[ks], bh, bl, o);
            }
            oacc[nt] = o;
        }
        __syncthreads();  // before next tile's staging overwrites K/V (and P)
    }

    // epilogue
    const float osc = (o_sidx >= 0) ? strat[o_sidx] : 1.0f;
#pragma unroll
    for (int reg = 0; reg < 4; ++reg) {
        float lf = masked ? (float)Tk : lreg[reg];
        int row = r0 + mbase + quad * 4 + reg;
        if (c == 0) {
            mout[h * Tq + row] = masked ? 0.0f : mreg[reg];
            lout[h * Tq + row] = lf;
        }
        float sc = osc / lf;
#pragma unroll
        for (int nt = 0; nt < NT_O; ++nt) {
            size_t gi = (size_t)row * D_MODEL + h * HD + nt * 16 + c;
            float v = sc * oacc[nt][reg];
            if (accum) v += O[gi];
            O[gi] = v;
        }
    }
}

// ---------------------------------------------------------------------------
// MFMA comb plane: comb[r][c] = csc * (sum_h exp(ascale_h*q_h.k_h - m)/l + unif/Tk)
// Block = 64 rows x 128 cols, loops 16 heads (HD=64). One store per element.
// ---------------------------------------------------------------------------
__global__ __launch_bounds__(256) void comb_mfma(
    const float* __restrict__ Q, const float* __restrict__ K,
    const float* __restrict__ mrow, const float* __restrict__ lrow,
    const float* __restrict__ aparam, int amode,
    const float* __restrict__ strat,
    float* __restrict__ comb, int Tq, int Tk, int nh, float inv_scale)
{
    __shared__ unsigned short Qh[64][72], Ql[64][72];
    __shared__ unsigned short Kh[128][72], Kl[128][72];
    const int tid = threadIdx.x;
    const int r0 = blockIdx.x * 64, c0 = blockIdx.y * 128;
    const int lane = tid & 63, wave = tid >> 6;
    const int c = lane & 15, quad = lane >> 4;
    const int mbase = wave * 16;

    f32x4 acc[8];
#pragma unroll
    for (int nt = 0; nt < 8; ++nt) acc[nt] = (f32x4){0.f, 0.f, 0.f, 0.f};
    float unif = 0.0f;

    for (int h = 0; h < nh; ++h) {
        float gate = 1.0f;
        if (amode == 1) gate = (aparam[h] > 0.0f) ? 1.0f : 0.0f;
        if (amode == 2) gate = 1.0f / (1.0f + __expf(-aparam[h * 4]));
        if (amode == 1 && gate == 0.0f) { unif += 1.0f; continue; }  // block-uniform
        const float ascale = gate * inv_scale;

        __syncthreads();   // previous head's tiles fully consumed
        for (int idx = tid; idx < 64 * 16; idx += 256) {        // Q 64x64
            int r = idx >> 4, d4 = (idx & 15) * 4;
            float4 v = *(const float4*)&Q[(size_t)(r0 + r) * D_MODEL + h * 64 + d4];
            ushort4 hs, ls;
            split2(v.x, hs.x, ls.x); split2(v.y, hs.y, ls.y);
            split2(v.z, hs.z, ls.z); split2(v.w, hs.w, ls.w);
            *(ushort4*)&Qh[r][d4] = hs; *(ushort4*)&Ql[r][d4] = ls;
        }
        for (int idx = tid; idx < 128 * 16; idx += 256) {       // K 128x64
            int r = idx >> 4, d4 = (idx & 15) * 4;
            float4 v = *(const float4*)&K[(size_t)(c0 + r) * D_MODEL + h * 64 + d4];
            ushort4 hs, ls;
            split2(v.x, hs.x, ls.x); split2(v.y, hs.y, ls.y);
            split2(v.z, hs.z, ls.z); split2(v.w, hs.w, ls.w);
            *(ushort4*)&Kh[r][d4] = hs; *(ushort4*)&Kl[r][d4] = ls;
        }
        __syncthreads();

        float mr[4], li[4];
#pragma unroll
        for (int reg = 0; reg < 4; ++reg) {
            int row = r0 + mbase + quad * 4 + reg;
            mr[reg] = mrow[h * Tq + row];
            li[reg] = 1.0f / lrow[h * Tq + row];
        }
        bf16x8 qah[2], qal[2];
#pragma unroll
        for (int ks = 0; ks < 2; ++ks) {
            qah[ks] = *(const bf16x8*)&Qh[mbase + c][ks * 32 + quad * 8];
            qal[ks] = *(const bf16x8*)&Ql[mbase + c][ks * 32 + quad * 8];
        }
#pragma unroll
        for (int nt = 0; nt < 8; ++nt) {
            f32x4 s = (f32x4){0.f, 0.f, 0.f, 0.f};
#pragma unroll
            for (int ks = 0; ks < 2; ++ks) {
                bf16x8 bh = *(const bf16x8*)&Kh[nt * 16 + c][ks * 32 + quad * 8];
                bf16x8 bl = *(const bf16x8*)&Kl[nt * 16 + c][ks * 32 + quad * 8];
                s = mfma3(qah[ks], qal[ks], bh, bl, s);
            }
#pragma unroll
            for (int reg = 0; reg < 4; ++reg)
                acc[nt][reg] += __expf(s[reg] * ascale - mr[reg]) * li[reg];
        }
    }
    const float csc = (strat[0] + strat[1] + strat[3]) / (float)nh;
    const float uadd = unif / (float)Tk;
#pragma unroll
    for (int nt = 0; nt < 8; ++nt) {
#pragma unroll
        for (int reg = 0; reg < 4; ++reg) {
            int row = r0 + mbase + quad * 4 + reg;
            comb[(size_t)row * Tk + c0 + nt * 16 + c] = csc * (acc[nt][reg] + uadd);
        }
    }
}

// ---------------------------------------------------------------------------
// Per-head 64x64 rotation (fp32, small): Y[t][h*64+e] = sum_d X[t][h*64+d]*R[h][d][e]
// ---------------------------------------------------------------------------
__global__ __launch_bounds__(256) void rotate_heads(
    const float* __restrict__ X, const float* __restrict__ R,
    float* __restrict__ Y)
{
    __shared__ float Rt[64][68];
    __shared__ float xs[64][68];
    const int tid = threadIdx.x;
    const int h = blockIdx.y;
    const int t0 = blockIdx.x * 64;
    for (int idx = tid; idx < 4096; idx += 256) {
        int d = idx >> 6, e = idx & 63;
        Rt[e][d] = R[h * 4096 + idx];
        xs[d][e] = X[(size_t)(t0 + d) * D_MODEL + h * 64 + e];
    }
    __syncthreads();
    const int ty = tid >> 4, tx = tid & 15;
    float acc[4][4] = {};
#pragma unroll 4
    for (int d0 = 0; d0 < 64; d0 += 4) {
        float4 rv[4];
#pragma unroll
        for (int j = 0; j < 4; ++j) rv[j] = *(const float4*)&Rt[tx * 4 + j][d0];
#pragma unroll
        for (int i = 0; i < 4; ++i) {
            float4 a = *(const float4*)&xs[ty * 4 + i][d0];
#pragma unroll
            for (int j = 0; j < 4; ++j)
                acc[i][j] += a.x * rv[j].x + a.y * rv[j].y + a.z * rv[j].z + a.w * rv[j].w;
        }
    }
#pragma unroll
    for (int i = 0; i < 4; ++i)
#pragma unroll
        for (int j = 0; j < 4; ++j)
            Y[(size_t)(t0 + ty * 4 + i) * D_MODEL + h * 64 + tx * 4 + j] = acc[i][j];
}

// ---------------------------------------------------------------------------
// F.interpolate(mode='linear', align_corners=False): [256,1024] -> [2048,1024]
// ---------------------------------------------------------------------------
__global__ __launch_bounds__(256) void interp_lin(
    const float* __restrict__ G, float* __restrict__ out)
{
    const int t = blockIdx.x;
    float src = (t + 0.5f) * 0.125f - 0.5f;
    src = fminf(fmaxf(src, 0.0f), 255.0f);
    float fl = floorf(src);
    int i0 = (int)fl;
    int i1 = min(i0 + 1, 255);
    float w = src - fl;
    const float4* g0 = (const float4*)(G + (size_t)i0 * D_MODEL);
    const float4* g1 = (const float4*)(G + (size_t)i1 * D_MODEL);
    float4* o = (float4*)(out + (size_t)t * D_MODEL);
    int c = threadIdx.x;
    float4 a = g0[c], b = g1[c];
    float4 r;
    r.x = a.x * (1.0f - w) + b.x * w;
    r.y = a.y * (1.0f - w) + b.y * w;
    r.z = a.z * (1.0f - w) + b.z * w;
    r.w = a.w * (1.0f - w) + b.w * w;
    o[c] = r;
}

// ---------------------------------------------------------------------------
extern "C" void kernel_launch(void* const* d_in, const int* in_sizes, int n_in,
                              void* d_out, int out_size, void* d_ws, size_t ws_size,
                              hipStream_t stream)
{
    (void)in_sizes; (void)n_in; (void)ws_size; (void)out_size;
    const float* query    = (const float*)d_in[0];
    const float* key      = (const float*)d_in[1];
    const float* value    = (const float*)d_in[2];
    const float* strat    = (const float*)d_in[3];
    const float* Wqkv_lin = (const float*)d_in[4];
    const float* b_lin    = (const float*)d_in[5];
    const float* Wo_lin   = (const float*)d_in[6];
    const float* bo_lin   = (const float*)d_in[7];
    const float* spars    = (const float*)d_in[8];
    const float* Wqkv_loc = (const float*)d_in[9];
    const float* b_loc    = (const float*)d_in[10];
    const float* Wo_loc   = (const float*)d_in[11];
    const float* bo_loc   = (const float*)d_in[12];
    const float* Wqkv_glb = (const float*)d_in[13];
    const float* b_glb    = (const float*)d_in[14];
    const float* Wo_glb   = (const float*)d_in[15];
    const float* bo_glb   = (const float*)d_in[16];
    const float* Wf       = (const float*)d_in[17];
    const float* bf       = (const float*)d_in[18];
    const float* Rq       = (const float*)d_in[19];
    const float* ent      = (const float*)d_in[20];

    float* out = (float*)d_out;
    float* weighted = out;                        // [2048][1024]
    float* combined = out + (size_t)2048 * 1024;  // [3][2048][2048]
    const size_t PLANE = (size_t)2048 * 2048;

    float* ws   = (float*)d_ws;
    float* qkv  = ws;                   // 3 x 2048x1024
    float* AO   = qkv + 6291456;
    float* LO   = AO + 2097152;
    float* gqkv = LO + 2097152;
    float* gAO  = gqkv + 786432;
    float* gOUT = gAO + 262144;
    float* GI   = gOUT + 262144;
    float* mb   = GI + 2097152;
    float* lb   = mb + 32768;
    float* qrot = qkv;                  // alias: lin qkv dead by then
    float* krot = qkv + 2097152;

    const float inv8   = 0.125f;
    const float inv128 = 1.0f / sqrtf(128.0f);
    const float* srcs[3] = {query, key, value};

    hipMemsetAsync(weighted, 0, (size_t)2097152 * sizeof(float), stream);

    // ---- LINEAR (proj'd MHA, 16 heads; combined plane 0) ----
    for (int sl = 0; sl < 3; ++sl)
        gemm_mfma<<<dim3(32, 16), 256, 0, stream>>>(
            srcs[sl], 1024, Wqkv_lin + (size_t)sl * 1048576, 1024, b_lin + sl * 1024,
            qkv + (size_t)sl * 2097152, 2048, 1024, 1024, nullptr, 0, 0);
    flash_mfma<64><<<dim3(32, 16), 256, 0, stream>>>(
        qkv, qkv + 2097152, qkv + 4194304, nullptr, 0,
        AO, strat, -1, 0, mb, lb, 2048, 2048, inv8);
    comb_mfma<<<dim3(32, 16), 256, 0, stream>>>(
        qkv, qkv + 2097152, mb, lb, nullptr, 0, strat,
        combined + 0 * PLANE, 2048, 2048, 16, inv8);
    gemm_mfma<<<dim3(32, 16), 256, 0, stream>>>(
        AO, 1024, Wo_lin, 1024, bo_lin, weighted, 2048, 1024, 1024, strat, 0, 1);

    // ---- SPARSE (raw heads, per-head mask; combined plane 1) ----
    flash_mfma<64><<<dim3(32, 16), 256, 0, stream>>>(
        query, key, value, spars, 1,
        weighted, strat, 1, 1, mb, lb, 2048, 2048, inv8);
    comb_mfma<<<dim3(32, 16), 256, 0, stream>>>(
        query, key, mb, lb, spars, 1, strat,
        combined + 1 * PLANE, 2048, 2048, 16, inv8);

    // ---- QUANTUM (rotated raw heads, per-head gate; combined plane 2) ----
    rotate_heads<<<dim3(32, 16), 256, 0, stream>>>(query, Rq, qrot);
    rotate_heads<<<dim3(32, 16), 256, 0, stream>>>(key, Rq, krot);
    flash_mfma<64><<<dim3(32, 16), 256, 0, stream>>>(
        qrot, krot, value, ent, 2,
        weighted, strat, 3, 1, mb, lb, 2048, 2048, inv8);
    comb_mfma<<<dim3(32, 16), 256, 0, stream>>>(
        qrot, krot, mb, lb, ent, 2, strat,
        combined + 2 * PLANE, 2048, 2048, 16, inv8);

    // ---- LOCAL (proj'd MHA, 8 heads x 128) ----
    for (int sl = 0; sl < 3; ++sl)
        gemm_mfma<<<dim3(32, 16), 256, 0, stream>>>(
            srcs[sl], 1024, Wqkv_loc + (size_t)sl * 1048576, 1024, b_loc + sl * 1024,
            qkv + (size_t)sl * 2097152, 2048, 1024, 1024, nullptr, 0, 0);
    flash_mfma<128><<<dim3(32, 8), 256, 0, stream>>>(
        qkv, qkv + 2097152, qkv + 4194304, nullptr, 0,
        AO, strat, -1, 0, mb, lb, 2048, 2048, inv128);
    gemm_mfma<<<dim3(32, 16), 256, 0, stream>>>(
        AO, 1024, Wo_loc, 1024, bo_loc, LO, 2048, 1024, 1024, nullptr, 0, 0);

    // ---- GLOBAL (strided pool to 256 tokens, 8 heads x 128, interp back) ----
    for (int sl = 0; sl < 3; ++sl)
        gemm_mfma<<<dim3(4, 16), 256, 0, stream>>>(
            srcs[sl], 8192, Wqkv_glb + (size_t)sl * 1048576, 1024, b_glb + sl * 1024,
            gqkv + (size_t)sl * 262144, 256, 1024, 1024, nullptr, 0, 0);
    flash_mfma<128><<<dim3(4, 8), 256, 0, stream>>>(
        gqkv, gqkv + 262144, gqkv + 524288, nullptr, 0,
        gAO, strat, -1, 0, mb, lb, 256, 256, inv128);
    gemm_mfma<<<dim3(4, 16), 256, 0, stream>>>(
        gAO, 1024, Wo_glb, 1024, bo_glb, gOUT, 256, 1024, 1024, nullptr, 0, 0);
    interp_lin<<<dim3(2048), 256, 0, stream>>>(gOUT, GI);

    // ---- HIER: weighted += s2 * (LO @ WfL^T + GI @ WfR^T + bf) ----
    gemm_mfma<<<dim3(32, 16), 256, 0, stream>>>(
        LO, 1024, Wf, 2048, bf, weighted, 2048, 1024, 1024, strat, 2, 1);
    gemm_mfma<<<dim3(32, 16), 256, 0, stream>>>(
        GI, 1024, Wf + 1024, 2048, nullptr, weighted, 2048, 1024, 1024, strat, 2, 1);
}